// Round 15
// baseline (363.195 us; speedup 1.0000x reference)
//
#include <hip/hip_runtime.h>
#include <hip/hip_bf16.h>
#include <stdint.h>

#define DEV __device__ __forceinline__

typedef float f32x4 __attribute__((ext_vector_type(4)));
typedef float f32x2 __attribute__((ext_vector_type(2)));

constexpr int nB = 64;
constexpr int nL = 1024;
constexpr int nD = 2048;
constexpr int nH = 128;

constexpr int NT = 16;          // L tiles for mean
constexpr int LT = nL / NT;     // 64 rows per tile

constexpr size_t X_ELEMS = (size_t)nB * (size_t)nL * (size_t)nD;  // 134217728

// ---------- math helpers (match JAX/XLA fp32 semantics closely) ----------
DEV float gelu_f(float x) {
  return 0.5f * x * (1.0f + erff(x * 0.7071067811865476f));
}
DEV float gelu_grad_f(float x) {
  return 0.5f * (1.0f + erff(x * 0.7071067811865476f))
       + x * 0.3989422804014327f * expf(-0.5f * x * x);
}
DEV float sigmoid_f(float x) { return 1.0f / (1.0f + expf(-x)); }

DEV uint32_t rotl32(uint32_t v, int r) { return (v << r) | (v >> (32 - r)); }

// ---------- fp8 e4m3fn encode/decode ----------
DEV uint8_t fp8_enc(float f) {
  if (!(f == f)) return 0;
  const uint32_t s = (__float_as_uint(f) >> 24) & 0x80u;
  float a = fabsf(f);
  if (a >= 448.f) return (uint8_t)(s | 0x7Eu);
  if (a < 0.015625f) {                       // subnormal: q = rint(a*2^9)
    const float q = rintf(a * 512.f);
    if (q >= 8.f) return (uint8_t)(s | 0x08u);
    return (uint8_t)(s | (uint32_t)q);
  }
  int E; const float fr = frexpf(a, &E);     // a = fr*2^E, fr in [0.5,1)
  float q = rintf(fr * 16.f);                // [8,16]
  int e = E + 6;                             // e4m3 exp field
  if (q >= 16.f) { q = 8.f; e += 1; }
  if (e > 15) return (uint8_t)(s | 0x7Eu);
  return (uint8_t)(s | ((uint32_t)e << 3) | ((uint32_t)q - 8u));
}

#if __has_builtin(__builtin_amdgcn_cvt_pk_f32_fp8)
template <bool HI>
DEV f32x2 fp8_pair(uint32_t w) {
  return __builtin_amdgcn_cvt_pk_f32_fp8(w, HI ? 1 : 0);  // imm word-select
}
#else
DEV float fp8_dec1(uint32_t b) {
  const uint32_t s = (b & 0x80u) << 24;
  const uint32_t em = b & 0x7Fu;
  float v;
  if (em >= 8u) v = __uint_as_float((((em >> 3) + 120u) << 23) | ((em & 7u) << 20));
  else          v = (float)em * 0.001953125f;   // 2^-9
  return __uint_as_float(__float_as_uint(v) | s);
}
template <bool HI>
DEV f32x2 fp8_pair(uint32_t w) {
  const uint32_t sh = HI ? 16u : 0u;
  f32x2 r = {fp8_dec1((w >> sh) & 0xFFu), fp8_dec1((w >> (sh + 8)) & 0xFFu)};
  return r;
}
#endif

// Threefry-2x32 with key (0,1)  == jax.random.key(1)
DEV void threefry_key01(uint32_t& x0, uint32_t& x1) {
  const uint32_t ks0 = 0u, ks1 = 1u, ks2 = 0x1BD11BDAu ^ 0u ^ 1u;
  x0 += ks0; x1 += ks1;
#define TF_RND(r) { x0 += x1; x1 = rotl32(x1, (r)); x1 ^= x0; }
  TF_RND(13) TF_RND(15) TF_RND(26) TF_RND(6)
  x0 += ks1; x1 += ks2 + 1u;
  TF_RND(17) TF_RND(29) TF_RND(16) TF_RND(24)
  x0 += ks2; x1 += ks0 + 2u;
  TF_RND(13) TF_RND(15) TF_RND(26) TF_RND(6)
  x0 += ks0; x1 += ks1 + 3u;
  TF_RND(17) TF_RND(29) TF_RND(16) TF_RND(24)
  x0 += ks1; x1 += ks2 + 4u;
  TF_RND(13) TF_RND(15) TF_RND(26) TF_RND(6)
  x0 += ks2; x1 += ks0 + 5u;
#undef TF_RND
}

// XLA ErfInv32 (Giles single-precision polynomial)
DEV float erfinv_f32(float x) {
  float w = -log1pf(-x * x);
  float p;
  if (w < 5.0f) {
    w -= 2.5f;
    p = 2.81022636e-08f;
    p = fmaf(p, w, 3.43273939e-07f);
    p = fmaf(p, w, -3.5233877e-06f);
    p = fmaf(p, w, -4.39150654e-06f);
    p = fmaf(p, w, 0.00021858087f);
    p = fmaf(p, w, -0.00125372503f);
    p = fmaf(p, w, -0.00417768164f);
    p = fmaf(p, w, 0.246640727f);
    p = fmaf(p, w, 1.50140941f);
  } else {
    w = sqrtf(w) - 3.0f;
    p = -0.000200214257f;
    p = fmaf(p, w, 0.000100950558f);
    p = fmaf(p, w, 0.00134934322f);
    p = fmaf(p, w, -0.00367342844f);
    p = fmaf(p, w, 0.00573950773f);
    p = fmaf(p, w, -0.0076224613f);
    p = fmaf(p, w, 0.00943887047f);
    p = fmaf(p, w, 1.00167406f);
    p = fmaf(p, w, 2.83297682f);
  }
  return p * x;
}

// jax.random.normal(key(1), (64,2048), f32), element i of row-major flat array
DEV float jax_normal_key1(int i) {
  const uint32_t j = (uint32_t)(i & 0xFFFF);
  uint32_t x0 = j, x1 = j + 65536u;
  threefry_key01(x0, x1);
  const uint32_t bits = (i < 65536) ? x0 : x1;
  const float u01 = __uint_as_float((bits >> 9) | 0x3F800000u) - 1.0f;
  const float lo = __uint_as_float(0xBF7FFFFFu);   // nextafter(-1,0)
  float v = u01 * 2.0f + lo;
  v = fmaxf(lo, v);
  return 1.4142135623730951f * erfinv_f32(v);
}

// ---------- K1: fused copy x->out + deterministic partial mean ----------
// Measured r10: 185 us standalone = 5.8 TB/s (92% of copy ceiling). Unchanged.
__global__ __launch_bounds__(512) void k_copy_mean(
    const float* __restrict__ x, float* __restrict__ out,
    float* __restrict__ pmean)
{
  const int blk = blockIdx.x;            // = b*16 + tile
  const int t = threadIdx.x;             // 0..511
  const size_t base = (size_t)blk * LT * nD;
  const size_t o = (size_t)4 * t;        // d in [0,2048)
  f32x4 a = {0.f, 0.f, 0.f, 0.f};
  for (int l = 0; l < LT; l += 2) {
    const size_t r0 = base + (size_t)l * nD;
    const size_t r1 = r0 + nD;
    const f32x4 v0 = __builtin_nontemporal_load(
        reinterpret_cast<const f32x4*>(x + r0 + o));
    const f32x4 v1 = __builtin_nontemporal_load(
        reinterpret_cast<const f32x4*>(x + r1 + o));
    __builtin_nontemporal_store(v0, reinterpret_cast<f32x4*>(out + r0 + o));
    __builtin_nontemporal_store(v1, reinterpret_cast<f32x4*>(out + r1 + o));
    a += v0;
    a += v1;
  }
  *reinterpret_cast<f32x4*>(pmean + (size_t)blk * nD + o) = a;
}

// fallback when ws is small: atomic accumulate directly into pooled
__global__ __launch_bounds__(256) void k_copy_mean_atomic(
    const float* __restrict__ x, float* __restrict__ out,
    float* __restrict__ pooled)
{
  const int blk = blockIdx.x;
  const int b = blk >> 4;
  const int t = threadIdx.x;
  const size_t base = (size_t)blk * LT * nD;
  const size_t o0 = (size_t)4 * t;
  const size_t o1 = 1024 + (size_t)4 * t;
  f32x4 a0 = {0.f, 0.f, 0.f, 0.f};
  f32x4 a1 = {0.f, 0.f, 0.f, 0.f};
  for (int l = 0; l < LT; ++l) {
    const size_t r = base + (size_t)l * nD;
    const f32x4 v0 = *reinterpret_cast<const f32x4*>(x + r + o0);
    const f32x4 v1 = *reinterpret_cast<const f32x4*>(x + r + o1);
    *reinterpret_cast<f32x4*>(out + r + o0) = v0;
    *reinterpret_cast<f32x4*>(out + r + o1) = v1;
    a0 += v0; a1 += v1;
  }
  float* pp = pooled + (size_t)b * nD;
  const float sc = 1.0f / nL;
  atomicAdd(&pp[o0+0], a0.x*sc); atomicAdd(&pp[o0+1], a0.y*sc);
  atomicAdd(&pp[o0+2], a0.z*sc); atomicAdd(&pp[o0+3], a0.w*sc);
  atomicAdd(&pp[o1+0], a1.x*sc); atomicAdd(&pp[o1+1], a1.y*sc);
  atomicAdd(&pp[o1+2], a1.z*sc); atomicAdd(&pp[o1+3], a1.w*sc);
}

// ---------- K0: W1 f32 -> packed fp8 arrays (x16 scale) — r12 layouts ----------
__global__ __launch_bounds__(256) void k_prep(
    const float* __restrict__ W1, uint32_t* __restrict__ w8f,
    uint32_t* __restrict__ w8b)
{
  __shared__ float tile[64][65];
  const int bd = blockIdx.x;   // 0..31  (d block of 64)
  const int bh = blockIdx.y;   // 0..1   (h block of 64)
  const int t = threadIdx.x;
  {
    const int j = t & 63;
    const int i0 = (t >> 6) * 16;
    for (int ii = 0; ii < 16; ++ii) {
      const int i = i0 + ii;
      tile[i][j] = W1[(size_t)(bd * 64 + i) * nH + bh * 64 + j];
    }
  }
  __syncthreads();
  const int j2 = t & 31;          // local h-pair
  const int ig = t >> 5;          // 0..7
  for (int k = 0; k < 4; ++k) {
    const int i2 = ig * 4 + k;    // local d-pair
    const uint32_t A = fp8_enc(16.f * tile[2 * i2][2 * j2]);
    const uint32_t B = fp8_enc(16.f * tile[2 * i2][2 * j2 + 1]);
    const uint32_t C = fp8_enc(16.f * tile[2 * i2 + 1][2 * j2]);
    const uint32_t D = fp8_enc(16.f * tile[2 * i2 + 1][2 * j2 + 1]);
    const int d2 = bd * 32 + i2;
    const int hp = bh * 32 + j2;
    w8f[(size_t)d2 * 64 + hp]  = A | (B << 8) | (C << 16) | (D << 24);
    w8b[(size_t)hp * 1024 + d2] = A | (C << 8) | (B << 16) | (D << 24);
  }
}

// ---------- K2: whole PGD loop, one block per batch ----------
// r12 structure (bwd reverted to load-based — r14 showed wreg >= neutral
// harm). Single change: fwd fully unrolled with 4 independent partial
// accumulators so the compiler can hoist load bursts ahead of the fma
// chain (deeper L2 pipelining; reassociation free in the fp8 path).
__global__ __launch_bounds__(1024) void k_pgd(
    const float* __restrict__ W1, const uint32_t* __restrict__ w8f,
    const uint32_t* __restrict__ w8b,
    const float* __restrict__ b1, const float* __restrict__ W2,
    const float* __restrict__ b2, const float* __restrict__ pmean,
    const float* __restrict__ pooledG, float* __restrict__ scores,
    const int from_partial)
{
  __shared__ float xaS[nD];
  __shared__ float pooledS[nD];
  __shared__ float redS[16][nH];
  __shared__ float dz1S[nH];
  __shared__ float red2[2];

  const int t = threadIdx.x;       // 0..1023
  const int b = blockIdx.x;        // 0..63

  // init: pooled + threefry noise -> xa0 (2 d per thread)
  {
    float2 pl;
    if (from_partial) {
      float2 s = make_float2(0.f, 0.f);
      for (int nt2 = 0; nt2 < NT; ++nt2) {
        const float2 v = *reinterpret_cast<const float2*>(
            &pmean[((size_t)(b * NT + nt2)) * nD + 2 * t]);
        s.x += v.x; s.y += v.y;
      }
      pl = make_float2(s.x * (1.0f / nL), s.y * (1.0f / nL));
    } else {
      pl = *reinterpret_cast<const float2*>(&pooledG[(size_t)b * nD + 2 * t]);
    }
    pooledS[2 * t]     = pl.x;
    pooledS[2 * t + 1] = pl.y;
    const int i0 = b * nD + 2 * t;
    xaS[2 * t]     = pl.x + 0.01f * jax_normal_key1(i0);
    xaS[2 * t + 1] = pl.y + 0.01f * jax_normal_key1(i0 + 1);
  }

  const float b1t = (t < nH) ? b1[t] : 0.f;
  const float w2t = (t < nH) ? W2[t] : 0.f;
  const float b2s = b2[0];

  __syncthreads();

  // fp8 fwd mapping: hp = h-pair 0..63, q = d-chunk 0..15 (128 d each)
  const int hp = t & 63;
  const int q  = t >> 6;
  // fp32 final mapping: h = t&127, dq = t>>7 (256 d each)
  const int hf = t & (nH - 1);
  const int dq = t >> 7;

  float sig_last = 0.f;
  for (int it = 0; it <= 10; ++it) {
    float z1 = 0.f;
    if (it < 10) {
      // ---- fp8 forward: FULLY unrolled, 4 independent accumulators ----
      f32x2 a0 = {0.f, 0.f}, a1 = {0.f, 0.f}, a2 = {0.f, 0.f}, a3 = {0.f, 0.f};
      const int dbase = q * 128;    // d base; d2 base = q*64
      #pragma unroll
      for (int k2 = 0; k2 < 32; ++k2) {
        const f32x4 xv = *reinterpret_cast<const f32x4*>(&xaS[dbase + 4 * k2]);
        const uint32_t wa = w8f[(size_t)(q * 64 + 2 * k2) * 64 + hp];
        const uint32_t wb = w8f[(size_t)(q * 64 + 2 * k2 + 1) * 64 + hp];
        a0 += xv[0] * fp8_pair<false>(wa);
        a1 += xv[1] * fp8_pair<true>(wa);
        a2 += xv[2] * fp8_pair<false>(wb);
        a3 += xv[3] * fp8_pair<true>(wb);
      }
      const f32x2 acc2 = (a0 + a2) + (a1 + a3);
      redS[q][2 * hp]     = acc2.x * 0.0625f;   // undo x16 weight scale
      redS[q][2 * hp + 1] = acc2.y * 0.0625f;
      __syncthreads();
      if (t < nH) {
        #pragma unroll
        for (int q2 = 0; q2 < 16; ++q2) z1 += redS[q2][t];
        z1 += b1t;
      }
    } else {
      // ---- fp32 final forward: round-2 exact arithmetic ----
      float acc = 0.f;
      const float* __restrict__ w1p = W1 + (size_t)(dq * 256) * nH + hf;
      #pragma unroll 8
      for (int d = 0; d < 256; ++d)
        acc = fmaf(xaS[dq * 256 + d], w1p[(size_t)d * nH], acc);
      redS[dq][hf] = acc;
      __syncthreads();
      if (t < nH) {
        #pragma unroll
        for (int q2 = 0; q2 < 8; ++q2) z1 += redS[q2][t];
        z1 += b1t;
      }
    }

    if (t < nH) {
      float part = gelu_f(z1) * w2t;
      #pragma unroll
      for (int m = 1; m <= 32; m <<= 1) part += __shfl_xor(part, m, 64);
      if ((t & 63) == 0) red2[t >> 6] = part;
    }
    __syncthreads();

    const float sig = sigmoid_f(red2[0] + red2[1] + b2s);
    if (it == 10) { sig_last = sig; break; }

    if (t < nH) dz1S[t] = sig * (1.f - sig) * w2t * gelu_grad_f(z1);
    __syncthreads();

    // ---- fp8 backward (r12 form): coalesced loads over h ----
    f32x2 g2 = {0.f, 0.f};
    #pragma unroll 8
    for (int mm = 0; mm < 32; ++mm) {     // 4 h per step
      const f32x4 dz4 = *reinterpret_cast<const f32x4*>(&dz1S[4 * mm]);
      const uint32_t wa = w8b[(size_t)(2 * mm) * 1024 + t];
      const uint32_t wb = w8b[(size_t)(2 * mm + 1) * 1024 + t];
      g2 += dz4[0] * fp8_pair<false>(wa);
      g2 += dz4[1] * fp8_pair<true>(wa);
      g2 += dz4[2] * fp8_pair<false>(wb);
      g2 += dz4[3] * fp8_pair<true>(wb);
    }
    const float gx = g2.x, gy = g2.y;     // scaled by 16 > 0: sign unchanged
    const float sg0 = (gx > 0.f) ? 1.f : ((gx < 0.f) ? -1.f : 0.f);
    const float sg1 = (gy > 0.f) ? 1.f : ((gy < 0.f) ? -1.f : 0.f);
    const float p0 = pooledS[2 * t], p1 = pooledS[2 * t + 1];
    float d0 = fminf(fmaxf((xaS[2 * t]     - 0.01f * sg0) - p0, -0.2f), 0.2f);
    float d1 = fminf(fmaxf((xaS[2 * t + 1] - 0.01f * sg1) - p1, -0.2f), 0.2f);
    xaS[2 * t]     = p0 + d0;
    xaS[2 * t + 1] = p1 + d1;
    __syncthreads();
  }

  if (t == 0) scores[b] = sig_last;
}

// ---------- zero helper (graph-capture safe; fallback path only) ----------
__global__ __launch_bounds__(256) void k_zero(float* __restrict__ p, int n) {
  const int i = blockIdx.x * 256 + threadIdx.x;
  if (i < n) p[i] = 0.f;
}

// ---------- tail outputs ----------
__global__ __launch_bounds__(64) void k_finalize(
    const float* __restrict__ scores, float* __restrict__ out)
{
  const int t = threadIdx.x;  // 0..63
  const float s = scores[t];
  out[X_ELEMS + t] = s;                    // worst_score
  out[X_ELEMS + nB + t] = 1.0f - s;        // cert_score
  float m = s;
  for (int o = 32; o > 0; o >>= 1) m = fminf(m, __shfl_xor(m, o, 64));
  if (t == 0) out[X_ELEMS + 2 * nB] = (m < 0.1f) ? 1.0f : 0.0f;  // violated
}

extern "C" void kernel_launch(void* const* d_in, const int* in_sizes, int n_in,
                              void* d_out, int out_size, void* d_ws, size_t ws_size,
                              hipStream_t stream) {
  const float* x  = (const float*)d_in[0];
  const float* W1 = (const float*)d_in[1];
  const float* b1 = (const float*)d_in[2];
  const float* W2 = (const float*)d_in[3];
  const float* b2 = (const float*)d_in[4];
  float* out = (float*)d_out;
  float* ws = (float*)d_ws;

  constexpr size_t PMEAN_ELEMS  = (size_t)nB * NT * nD;   // 2,097,152 f32
  constexpr size_t POOLED_ELEMS = (size_t)nB * nD;        // 131,072 f32
  constexpr size_t W8_WORDS     = (size_t)1024 * 64;      // 65,536 u32 each
  const size_t primary_bytes =
      PMEAN_ELEMS * 4 + W8_WORDS * 4 * 2 + nB * 4;

  if (ws_size >= primary_bytes) {
    float*    pmean  = ws;
    uint32_t* w8f    = (uint32_t*)(ws + PMEAN_ELEMS);
    uint32_t* w8b    = w8f + W8_WORDS;
    float*    scores = (float*)(w8b + W8_WORDS);

    k_prep<<<dim3(32, 2), 256, 0, stream>>>(W1, w8f, w8b);
    k_copy_mean<<<nB * NT, 512, 0, stream>>>(x, out, pmean);
    k_pgd<<<nB, 1024, 0, stream>>>(W1, w8f, w8b, b1, W2, b2,
                                   pmean, nullptr, scores, 1);
    k_finalize<<<1, 64, 0, stream>>>(scores, out);
  } else {
    float*    pooled = ws;
    uint32_t* w8f    = (uint32_t*)(ws + POOLED_ELEMS);
    uint32_t* w8b    = w8f + W8_WORDS;
    float*    scores = (float*)(w8b + W8_WORDS);

    k_zero<<<(int)(POOLED_ELEMS + 255) / 256, 256, 0, stream>>>(
        pooled, (int)POOLED_ELEMS);
    k_prep<<<dim3(32, 2), 256, 0, stream>>>(W1, w8f, w8b);
    k_copy_mean_atomic<<<nB * NT, 256, 0, stream>>>(x, out, pooled);
    k_pgd<<<nB, 1024, 0, stream>>>(W1, w8f, w8b, b1, W2, b2,
                                   nullptr, pooled, scores, 0);
    k_finalize<<<1, 64, 0, stream>>>(scores, out);
  }
}

// Round 16
// 284.530 us; speedup vs baseline: 1.2765x; 1.2765x over previous
//
#include <hip/hip_runtime.h>
#include <hip/hip_bf16.h>
#include <stdint.h>

#define DEV __device__ __forceinline__

typedef float f32x4 __attribute__((ext_vector_type(4)));
typedef float f32x2 __attribute__((ext_vector_type(2)));

constexpr int nB = 64;
constexpr int nL = 1024;
constexpr int nD = 2048;
constexpr int nH = 128;

constexpr int NT = 16;          // L tiles for mean
constexpr int LT = nL / NT;     // 64 rows per tile

constexpr size_t X_ELEMS = (size_t)nB * (size_t)nL * (size_t)nD;  // 134217728

// ---------- math helpers (match JAX/XLA fp32 semantics closely) ----------
DEV float gelu_f(float x) {
  return 0.5f * x * (1.0f + erff(x * 0.7071067811865476f));
}
DEV float gelu_grad_f(float x) {
  return 0.5f * (1.0f + erff(x * 0.7071067811865476f))
       + x * 0.3989422804014327f * expf(-0.5f * x * x);
}
DEV float sigmoid_f(float x) { return 1.0f / (1.0f + expf(-x)); }

DEV uint32_t rotl32(uint32_t v, int r) { return (v << r) | (v >> (32 - r)); }

// ---------- fp8 e4m3fn encode/decode ----------
DEV uint8_t fp8_enc(float f) {
  if (!(f == f)) return 0;
  const uint32_t s = (__float_as_uint(f) >> 24) & 0x80u;
  float a = fabsf(f);
  if (a >= 448.f) return (uint8_t)(s | 0x7Eu);
  if (a < 0.015625f) {                       // subnormal: q = rint(a*2^9)
    const float q = rintf(a * 512.f);
    if (q >= 8.f) return (uint8_t)(s | 0x08u);
    return (uint8_t)(s | (uint32_t)q);
  }
  int E; const float fr = frexpf(a, &E);     // a = fr*2^E, fr in [0.5,1)
  float q = rintf(fr * 16.f);                // [8,16]
  int e = E + 6;                             // e4m3 exp field
  if (q >= 16.f) { q = 8.f; e += 1; }
  if (e > 15) return (uint8_t)(s | 0x7Eu);
  return (uint8_t)(s | ((uint32_t)e << 3) | ((uint32_t)q - 8u));
}

#if __has_builtin(__builtin_amdgcn_cvt_pk_f32_fp8)
template <bool HI>
DEV f32x2 fp8_pair(uint32_t w) {
  return __builtin_amdgcn_cvt_pk_f32_fp8(w, HI ? 1 : 0);  // imm word-select
}
#else
DEV float fp8_dec1(uint32_t b) {
  const uint32_t s = (b & 0x80u) << 24;
  const uint32_t em = b & 0x7Fu;
  float v;
  if (em >= 8u) v = __uint_as_float((((em >> 3) + 120u) << 23) | ((em & 7u) << 20));
  else          v = (float)em * 0.001953125f;   // 2^-9
  return __uint_as_float(__float_as_uint(v) | s);
}
template <bool HI>
DEV f32x2 fp8_pair(uint32_t w) {
  const uint32_t sh = HI ? 16u : 0u;
  f32x2 r = {fp8_dec1((w >> sh) & 0xFFu), fp8_dec1((w >> (sh + 8)) & 0xFFu)};
  return r;
}
#endif

// Threefry-2x32 with key (0,1)  == jax.random.key(1)
DEV void threefry_key01(uint32_t& x0, uint32_t& x1) {
  const uint32_t ks0 = 0u, ks1 = 1u, ks2 = 0x1BD11BDAu ^ 0u ^ 1u;
  x0 += ks0; x1 += ks1;
#define TF_RND(r) { x0 += x1; x1 = rotl32(x1, (r)); x1 ^= x0; }
  TF_RND(13) TF_RND(15) TF_RND(26) TF_RND(6)
  x0 += ks1; x1 += ks2 + 1u;
  TF_RND(17) TF_RND(29) TF_RND(16) TF_RND(24)
  x0 += ks2; x1 += ks0 + 2u;
  TF_RND(13) TF_RND(15) TF_RND(26) TF_RND(6)
  x0 += ks0; x1 += ks1 + 3u;
  TF_RND(17) TF_RND(29) TF_RND(16) TF_RND(24)
  x0 += ks1; x1 += ks2 + 4u;
  TF_RND(13) TF_RND(15) TF_RND(26) TF_RND(6)
  x0 += ks2; x1 += ks0 + 5u;
#undef TF_RND
}

// XLA ErfInv32 (Giles single-precision polynomial)
DEV float erfinv_f32(float x) {
  float w = -log1pf(-x * x);
  float p;
  if (w < 5.0f) {
    w -= 2.5f;
    p = 2.81022636e-08f;
    p = fmaf(p, w, 3.43273939e-07f);
    p = fmaf(p, w, -3.5233877e-06f);
    p = fmaf(p, w, -4.39150654e-06f);
    p = fmaf(p, w, 0.00021858087f);
    p = fmaf(p, w, -0.00125372503f);
    p = fmaf(p, w, -0.00417768164f);
    p = fmaf(p, w, 0.246640727f);
    p = fmaf(p, w, 1.50140941f);
  } else {
    w = sqrtf(w) - 3.0f;
    p = -0.000200214257f;
    p = fmaf(p, w, 0.000100950558f);
    p = fmaf(p, w, 0.00134934322f);
    p = fmaf(p, w, -0.00367342844f);
    p = fmaf(p, w, 0.00573950773f);
    p = fmaf(p, w, -0.0076224613f);
    p = fmaf(p, w, 0.00943887047f);
    p = fmaf(p, w, 1.00167406f);
    p = fmaf(p, w, 2.83297682f);
  }
  return p * x;
}

// jax.random.normal(key(1), (64,2048), f32), element i of row-major flat array
DEV float jax_normal_key1(int i) {
  const uint32_t j = (uint32_t)(i & 0xFFFF);
  uint32_t x0 = j, x1 = j + 65536u;
  threefry_key01(x0, x1);
  const uint32_t bits = (i < 65536) ? x0 : x1;
  const float u01 = __uint_as_float((bits >> 9) | 0x3F800000u) - 1.0f;
  const float lo = __uint_as_float(0xBF7FFFFFu);   // nextafter(-1,0)
  float v = u01 * 2.0f + lo;
  v = fmaxf(lo, v);
  return 1.4142135623730951f * erfinv_f32(v);
}

// ---------- K1: fused copy x->out + deterministic partial mean ----------
// Measured r10: 185 us standalone = 5.8 TB/s (92% of copy ceiling). Unchanged.
__global__ __launch_bounds__(512) void k_copy_mean(
    const float* __restrict__ x, float* __restrict__ out,
    float* __restrict__ pmean)
{
  const int blk = blockIdx.x;            // = b*16 + tile
  const int t = threadIdx.x;             // 0..511
  const size_t base = (size_t)blk * LT * nD;
  const size_t o = (size_t)4 * t;        // d in [0,2048)
  f32x4 a = {0.f, 0.f, 0.f, 0.f};
  for (int l = 0; l < LT; l += 2) {
    const size_t r0 = base + (size_t)l * nD;
    const size_t r1 = r0 + nD;
    const f32x4 v0 = __builtin_nontemporal_load(
        reinterpret_cast<const f32x4*>(x + r0 + o));
    const f32x4 v1 = __builtin_nontemporal_load(
        reinterpret_cast<const f32x4*>(x + r1 + o));
    __builtin_nontemporal_store(v0, reinterpret_cast<f32x4*>(out + r0 + o));
    __builtin_nontemporal_store(v1, reinterpret_cast<f32x4*>(out + r1 + o));
    a += v0;
    a += v1;
  }
  *reinterpret_cast<f32x4*>(pmean + (size_t)blk * nD + o) = a;
}

// fallback when ws is small: atomic accumulate directly into pooled
__global__ __launch_bounds__(256) void k_copy_mean_atomic(
    const float* __restrict__ x, float* __restrict__ out,
    float* __restrict__ pooled)
{
  const int blk = blockIdx.x;
  const int b = blk >> 4;
  const int t = threadIdx.x;
  const size_t base = (size_t)blk * LT * nD;
  const size_t o0 = (size_t)4 * t;
  const size_t o1 = 1024 + (size_t)4 * t;
  f32x4 a0 = {0.f, 0.f, 0.f, 0.f};
  f32x4 a1 = {0.f, 0.f, 0.f, 0.f};
  for (int l = 0; l < LT; ++l) {
    const size_t r = base + (size_t)l * nD;
    const f32x4 v0 = *reinterpret_cast<const f32x4*>(x + r + o0);
    const f32x4 v1 = *reinterpret_cast<const f32x4*>(x + r + o1);
    *reinterpret_cast<f32x4*>(out + r + o0) = v0;
    *reinterpret_cast<f32x4*>(out + r + o1) = v1;
    a0 += v0; a1 += v1;
  }
  float* pp = pooled + (size_t)b * nD;
  const float sc = 1.0f / nL;
  atomicAdd(&pp[o0+0], a0.x*sc); atomicAdd(&pp[o0+1], a0.y*sc);
  atomicAdd(&pp[o0+2], a0.z*sc); atomicAdd(&pp[o0+3], a0.w*sc);
  atomicAdd(&pp[o1+0], a1.x*sc); atomicAdd(&pp[o1+1], a1.y*sc);
  atomicAdd(&pp[o1+2], a1.z*sc); atomicAdd(&pp[o1+3], a1.w*sc);
}

// ---------- K0: W1 f32 -> packed fp8 arrays (x16 scale) ----------
// w8f[d2*64 + hp]  = bytes {W(d0,h0), W(d0,h1), W(d1,h0), W(d1,h1)}
// w8b[m*1024 + dp] = bytes {W(d0,h0), W(d1,h0), W(d0,h1), W(d1,h1)}
//   where d0=2*d2(dp), d1=d0+1, h0=2*hp(m), h1=h0+1, W = 16*W1[d][h]
__global__ __launch_bounds__(256) void k_prep(
    const float* __restrict__ W1, uint32_t* __restrict__ w8f,
    uint32_t* __restrict__ w8b)
{
  __shared__ float tile[64][65];
  const int bd = blockIdx.x;   // 0..31  (d block of 64)
  const int bh = blockIdx.y;   // 0..1   (h block of 64)
  const int t = threadIdx.x;
  {
    const int j = t & 63;
    const int i0 = (t >> 6) * 16;
    for (int ii = 0; ii < 16; ++ii) {
      const int i = i0 + ii;
      tile[i][j] = W1[(size_t)(bd * 64 + i) * nH + bh * 64 + j];
    }
  }
  __syncthreads();
  const int j2 = t & 31;          // local h-pair
  const int ig = t >> 5;          // 0..7
  for (int k = 0; k < 4; ++k) {
    const int i2 = ig * 4 + k;    // local d-pair
    const uint32_t A = fp8_enc(16.f * tile[2 * i2][2 * j2]);
    const uint32_t B = fp8_enc(16.f * tile[2 * i2][2 * j2 + 1]);
    const uint32_t C = fp8_enc(16.f * tile[2 * i2 + 1][2 * j2]);
    const uint32_t D = fp8_enc(16.f * tile[2 * i2 + 1][2 * j2 + 1]);
    const int d2 = bd * 32 + i2;
    const int hp = bh * 32 + j2;
    w8f[(size_t)d2 * 64 + hp]  = A | (B << 8) | (C << 16) | (D << 24);
    w8b[(size_t)hp * 1024 + d2] = A | (C << 8) | (B << 16) | (D << 24);
  }
}

// ---------- K2: whole PGD loop, one block per batch ----------
// Iters 0..9: fp8 weights (x16 scaled; only sign(g) matters -> bwd never
// rescales). Final pass (it==10): round-2's exact fp32 arithmetic.
// r12 form exactly — every later perturbation (r13 wider loads, r14 reg
// weights, r15 deep unroll) was neutral or regressed.
__global__ __launch_bounds__(1024) void k_pgd(
    const float* __restrict__ W1, const uint32_t* __restrict__ w8f,
    const uint32_t* __restrict__ w8b,
    const float* __restrict__ b1, const float* __restrict__ W2,
    const float* __restrict__ b2, const float* __restrict__ pmean,
    const float* __restrict__ pooledG, float* __restrict__ scores,
    const int from_partial)
{
  __shared__ float xaS[nD];
  __shared__ float pooledS[nD];
  __shared__ float redS[16][nH];
  __shared__ float dz1S[nH];
  __shared__ float red2[2];

  const int t = threadIdx.x;       // 0..1023
  const int b = blockIdx.x;        // 0..63

  // init: pooled + threefry noise -> xa0 (2 d per thread)
  {
    float2 pl;
    if (from_partial) {
      float2 s = make_float2(0.f, 0.f);
      for (int nt2 = 0; nt2 < NT; ++nt2) {
        const float2 v = *reinterpret_cast<const float2*>(
            &pmean[((size_t)(b * NT + nt2)) * nD + 2 * t]);
        s.x += v.x; s.y += v.y;
      }
      pl = make_float2(s.x * (1.0f / nL), s.y * (1.0f / nL));
    } else {
      pl = *reinterpret_cast<const float2*>(&pooledG[(size_t)b * nD + 2 * t]);
    }
    pooledS[2 * t]     = pl.x;
    pooledS[2 * t + 1] = pl.y;
    const int i0 = b * nD + 2 * t;
    xaS[2 * t]     = pl.x + 0.01f * jax_normal_key1(i0);
    xaS[2 * t + 1] = pl.y + 0.01f * jax_normal_key1(i0 + 1);
  }

  const float b1t = (t < nH) ? b1[t] : 0.f;
  const float w2t = (t < nH) ? W2[t] : 0.f;
  const float b2s = b2[0];

  __syncthreads();

  // fp8 fwd mapping: hp = h-pair 0..63, q = d-chunk 0..15 (128 d each)
  const int hp = t & 63;
  const int q  = t >> 6;
  // fp32 final mapping: h = t&127, dq = t>>7 (256 d each)
  const int hf = t & (nH - 1);
  const int dq = t >> 7;

  float sig_last = 0.f;
  for (int it = 0; it <= 10; ++it) {
    float z1 = 0.f;
    if (it < 10) {
      // ---- fp8 forward: per 4 d = 1 b128 LDS + 2 loads + 4 cvt + 4 pk_fma
      f32x2 acc2 = {0.f, 0.f};
      const int dbase = q * 128;    // d base; d2 base = q*64
      #pragma unroll 8
      for (int k2 = 0; k2 < 32; ++k2) {
        const f32x4 xv = *reinterpret_cast<const f32x4*>(&xaS[dbase + 4 * k2]);
        const uint32_t wa = w8f[(size_t)(q * 64 + 2 * k2) * 64 + hp];
        const uint32_t wb = w8f[(size_t)(q * 64 + 2 * k2 + 1) * 64 + hp];
        acc2 += xv[0] * fp8_pair<false>(wa);
        acc2 += xv[1] * fp8_pair<true>(wa);
        acc2 += xv[2] * fp8_pair<false>(wb);
        acc2 += xv[3] * fp8_pair<true>(wb);
      }
      redS[q][2 * hp]     = acc2.x * 0.0625f;   // undo x16 weight scale
      redS[q][2 * hp + 1] = acc2.y * 0.0625f;
      __syncthreads();
      if (t < nH) {
        #pragma unroll
        for (int q2 = 0; q2 < 16; ++q2) z1 += redS[q2][t];
        z1 += b1t;
      }
    } else {
      // ---- fp32 final forward: round-2 exact arithmetic ----
      float acc = 0.f;
      const float* __restrict__ w1p = W1 + (size_t)(dq * 256) * nH + hf;
      #pragma unroll 8
      for (int d = 0; d < 256; ++d)
        acc = fmaf(xaS[dq * 256 + d], w1p[(size_t)d * nH], acc);
      redS[dq][hf] = acc;
      __syncthreads();
      if (t < nH) {
        #pragma unroll
        for (int q2 = 0; q2 < 8; ++q2) z1 += redS[q2][t];
        z1 += b1t;
      }
    }

    if (t < nH) {
      float part = gelu_f(z1) * w2t;
      #pragma unroll
      for (int m = 1; m <= 32; m <<= 1) part += __shfl_xor(part, m, 64);
      if ((t & 63) == 0) red2[t >> 6] = part;
    }
    __syncthreads();

    const float sig = sigmoid_f(red2[0] + red2[1] + b2s);
    if (it == 10) { sig_last = sig; break; }

    if (t < nH) dz1S[t] = sig * (1.f - sig) * w2t * gelu_grad_f(z1);
    __syncthreads();

    // ---- fp8 backward: g(2t,2t+1) = sum_h dz1[h]*W(d,h); x16 scale kept
    f32x2 g2 = {0.f, 0.f};
    #pragma unroll 8
    for (int mm = 0; mm < 32; ++mm) {     // 4 h per step
      const f32x4 dz4 = *reinterpret_cast<const f32x4*>(&dz1S[4 * mm]);
      const uint32_t wa = w8b[(size_t)(2 * mm) * 1024 + t];
      const uint32_t wb = w8b[(size_t)(2 * mm + 1) * 1024 + t];
      g2 += dz4[0] * fp8_pair<false>(wa);
      g2 += dz4[1] * fp8_pair<true>(wa);
      g2 += dz4[2] * fp8_pair<false>(wb);
      g2 += dz4[3] * fp8_pair<true>(wb);
    }
    const float gx = g2.x, gy = g2.y;     // scaled by 16 > 0: sign unchanged
    const float sg0 = (gx > 0.f) ? 1.f : ((gx < 0.f) ? -1.f : 0.f);
    const float sg1 = (gy > 0.f) ? 1.f : ((gy < 0.f) ? -1.f : 0.f);
    const float p0 = pooledS[2 * t], p1 = pooledS[2 * t + 1];
    float d0 = fminf(fmaxf((xaS[2 * t]     - 0.01f * sg0) - p0, -0.2f), 0.2f);
    float d1 = fminf(fmaxf((xaS[2 * t + 1] - 0.01f * sg1) - p1, -0.2f), 0.2f);
    xaS[2 * t]     = p0 + d0;
    xaS[2 * t + 1] = p1 + d1;
    __syncthreads();
  }

  if (t == 0) scores[b] = sig_last;
}

// ---------- zero helper (graph-capture safe; fallback path only) ----------
__global__ __launch_bounds__(256) void k_zero(float* __restrict__ p, int n) {
  const int i = blockIdx.x * 256 + threadIdx.x;
  if (i < n) p[i] = 0.f;
}

// ---------- tail outputs ----------
__global__ __launch_bounds__(64) void k_finalize(
    const float* __restrict__ scores, float* __restrict__ out)
{
  const int t = threadIdx.x;  // 0..63
  const float s = scores[t];
  out[X_ELEMS + t] = s;                    // worst_score
  out[X_ELEMS + nB + t] = 1.0f - s;        // cert_score
  float m = s;
  for (int o = 32; o > 0; o >>= 1) m = fminf(m, __shfl_xor(m, o, 64));
  if (t == 0) out[X_ELEMS + 2 * nB] = (m < 0.1f) ? 1.0f : 0.0f;  // violated
}

extern "C" void kernel_launch(void* const* d_in, const int* in_sizes, int n_in,
                              void* d_out, int out_size, void* d_ws, size_t ws_size,
                              hipStream_t stream) {
  const float* x  = (const float*)d_in[0];
  const float* W1 = (const float*)d_in[1];
  const float* b1 = (const float*)d_in[2];
  const float* W2 = (const float*)d_in[3];
  const float* b2 = (const float*)d_in[4];
  float* out = (float*)d_out;
  float* ws = (float*)d_ws;

  constexpr size_t PMEAN_ELEMS  = (size_t)nB * NT * nD;   // 2,097,152 f32
  constexpr size_t POOLED_ELEMS = (size_t)nB * nD;        // 131,072 f32
  constexpr size_t W8_WORDS     = (size_t)1024 * 64;      // 65,536 u32 each
  const size_t primary_bytes =
      PMEAN_ELEMS * 4 + W8_WORDS * 4 * 2 + nB * 4;

  if (ws_size >= primary_bytes) {
    float*    pmean  = ws;
    uint32_t* w8f    = (uint32_t*)(ws + PMEAN_ELEMS);
    uint32_t* w8b    = w8f + W8_WORDS;
    float*    scores = (float*)(w8b + W8_WORDS);

    k_prep<<<dim3(32, 2), 256, 0, stream>>>(W1, w8f, w8b);
    k_copy_mean<<<nB * NT, 512, 0, stream>>>(x, out, pmean);
    k_pgd<<<nB, 1024, 0, stream>>>(W1, w8f, w8b, b1, W2, b2,
                                   pmean, nullptr, scores, 1);
    k_finalize<<<1, 64, 0, stream>>>(scores, out);
  } else {
    float*    pooled = ws;
    uint32_t* w8f    = (uint32_t*)(ws + POOLED_ELEMS);
    uint32_t* w8b    = w8f + W8_WORDS;
    float*    scores = (float*)(w8b + W8_WORDS);

    k_zero<<<(int)(POOLED_ELEMS + 255) / 256, 256, 0, stream>>>(
        pooled, (int)POOLED_ELEMS);
    k_prep<<<dim3(32, 2), 256, 0, stream>>>(W1, w8f, w8b);
    k_copy_mean_atomic<<<nB * NT, 256, 0, stream>>>(x, out, pooled);
    k_pgd<<<nB, 1024, 0, stream>>>(W1, w8f, w8b, b1, W2, b2,
                                   nullptr, pooled, scores, 0);
    k_finalize<<<1, 64, 0, stream>>>(scores, out);
  }
}